// Round 16
// baseline (788.286 us; speedup 1.0000x reference)
//
#include <hip/hip_runtime.h>
#include <hip/hip_bf16.h>
#include <float.h>
#include <math.h>

typedef __hip_bfloat16 bf16;

#define B_ 16
#define N_ 1000
#define E_ 4000
#define L_ 64
#define A_ 128
#define D_ 256
#define H_ 4
#define HD_ 1024
#define SCALE_ 0.0625f
#define QS 5120   // fused projection stride: q|k|v|skip|qW

typedef __attribute__((ext_vector_type(8))) short short8;
typedef __attribute__((ext_vector_type(4))) float f32x4;

union U4S8 { uint4 u; short8 s; };

__device__ __forceinline__ unsigned short f2bf(float f) {
    bf16 h = __float2bfloat16(f);
    return *reinterpret_cast<unsigned short*>(&h);
}
__device__ __forceinline__ unsigned pack2(float a, float b) {
    return (unsigned)f2bf(a) | ((unsigned)f2bf(b) << 16);
}
__device__ __forceinline__ unsigned short rne1(float a) {
    unsigned ua = __float_as_uint(a);
    ua += 0x7fff + ((ua >> 16) & 1);
    return (unsigned short)(ua >> 16);
}
__device__ __forceinline__ float bflo(unsigned u) { return __uint_as_float(u << 16); }
__device__ __forceinline__ float bfhi(unsigned u) { return __uint_as_float(u & 0xffff0000u); }

#define LOG2E 1.4426950408889634f
__device__ __forceinline__ float fsigm(float x) {
    return __builtin_amdgcn_rcpf(1.f + __builtin_amdgcn_exp2f(-LOG2E * x));
}
__device__ __forceinline__ float ftanh(float x) {
    return 1.f - 2.f * __builtin_amdgcn_rcpf(1.f + __builtin_amdgcn_exp2f(2.f * LOG2E * x));
}

// async global->LDS, 16B per lane
typedef const __attribute__((address_space(1))) unsigned int* gas_t;
typedef __attribute__((address_space(3))) unsigned int* las_t;
__device__ __forceinline__ void gld16(const void* g, void* l) {
    __builtin_amdgcn_global_load_lds((gas_t)g, (las_t)l, 16, 0, 0);
}

// ---------------------------------------------------------------------------
// Pre-pass: emb->bf16
// ---------------------------------------------------------------------------
__global__ void convemb_kernel(const float* __restrict__ src, bf16* __restrict__ dst, long n4)
{
    long i = (long)blockIdx.x * 256 + threadIdx.x;
    if (i >= n4) return;
    float4 v = *(const float4*)(src + i * 4);
    *(uint2*)(dst + i * 4) = make_uint2(pack2(v.x, v.y), pack2(v.z, v.w));
}

// ---------------------------------------------------------------------------
// Fused weight-pack pre-pass (qkvsP has stride QS; cols 4096.. filled by wqe)
// ---------------------------------------------------------------------------
__global__ void pack_all_kernel(const float* __restrict__ Wq, const float* __restrict__ Wk,
                                const float* __restrict__ Wv, const float* __restrict__ Wskip,
                                const float* __restrict__ We, const float* __restrict__ W1,
                                const float* __restrict__ Wp, const float* __restrict__ W_ih,
                                const float* __restrict__ W_hh,
                                const float* __restrict__ bq, const float* __restrict__ bk,
                                const float* __restrict__ bv, const float* __restrict__ bskip,
                                unsigned* __restrict__ qkvsP, unsigned* __restrict__ WeP,
                                unsigned* __restrict__ W1P, unsigned* __restrict__ WpP,
                                unsigned* __restrict__ WihP,
                                short8* __restrict__ WhhP, float* __restrict__ bias5120)
{
    int i = blockIdx.x * 256 + threadIdx.x;
    if (i < 524288) {                       // qkvsP cols 0..4095: 128 k2 x 4096
        int k2 = i >> 12, n = i & 4095;
        const float* s = (n < 1024) ? Wq : (n < 2048) ? Wk : (n < 3072) ? Wv : Wskip;
        int col = n & 1023;
        qkvsP[(long)k2 * QS + n] =
            pack2(s[(long)(2 * k2) * 1024 + col], s[(long)(2 * k2 + 1) * 1024 + col]);
        return;
    }
    i -= 524288;
    if (i < 131072) {                       // WeP: 128 x 1024
        int k2 = i >> 10, n = i & 1023;
        WeP[i] = pack2(We[(long)(2 * k2) * 1024 + n], We[(long)(2 * k2 + 1) * 1024 + n]);
        return;
    }
    i -= 131072;
    if (i < 131072) {                       // W1P: 512 k2 x 256
        int k2 = i >> 8, n = i & 255;
        W1P[i] = pack2(W1[(long)(2 * k2) * 256 + n], W1[(long)(2 * k2 + 1) * 256 + n]);
        return;
    }
    i -= 131072;
    if (i < 32768) {                        // WpP: 128 x 256
        int k2 = i >> 8, n = i & 255;
        WpP[i] = pack2(Wp[(long)(2 * k2) * 256 + n], Wp[(long)(2 * k2 + 1) * 256 + n]);
        return;
    }
    i -= 32768;
    if (i < 98304) {                        // WihP (transposed src [768,256]): 128 k2 x 768
        int k2 = i / 768, n = i % 768;
        WihP[i] = pack2(W_ih[(long)n * 256 + 2 * k2], W_ih[(long)n * 256 + 2 * k2 + 1]);
        return;
    }
    i -= 98304;
    if (i < 24576) {                        // WhhP MFMA B-frag stream (48 tiles)
        int lane = i & 63, tk = (i >> 6) & 7, tile = i >> 9;
        int n = tile * 16 + (lane & 15);
        const float* wp = W_hh + (long)n * 256 + tk * 32 + (lane >> 4) * 8;
        float4 w0 = *(const float4*)wp;
        float4 w1 = *(const float4*)(wp + 4);
        U4S8 u;
        u.u = make_uint4(pack2(w0.x, w0.y), pack2(w0.z, w0.w),
                         pack2(w1.x, w1.y), pack2(w1.z, w1.w));
        WhhP[i] = u.s;
        return;
    }
    i -= 24576;
    if (i < 4096) {                         // bias cols 0..4095
        int q = i >> 10, c = i & 1023;
        bias5120[i] = ((q == 0) ? bq : (q == 1) ? bk : (q == 2) ? bv : bskip)[c];
    }
}
#define PACK_ALL_TOT (524288 + 131072 + 131072 + 32768 + 98304 + 24576 + 4096)

// ---------------------------------------------------------------------------
// Wqe = Wq_h @ We_h^T
// ---------------------------------------------------------------------------
__global__ __launch_bounds__(256)
void wqe_kernel(const float* __restrict__ Wq, const float* __restrict__ We,
                const float* __restrict__ bq,
                unsigned* __restrict__ qkvsP, float* __restrict__ bias5120)
{
    int k2 = blockIdx.x >> 2;
    int h  = blockIdx.x & 3;
    int d  = threadIdx.x;
    int hb = h * 256;
    __shared__ float w0[256], w1[256];
    w0[d] = Wq[(long)(2 * k2) * 1024 + hb + d];
    w1[d] = Wq[(long)(2 * k2 + 1) * 1024 + hb + d];
    __syncthreads();
    const float* wer = We + (long)d * 1024 + hb;
    float s0 = 0.f, s1 = 0.f;
    #pragma unroll 8
    for (int j = 0; j < 256; ++j) {
        float we = wer[j];
        s0 += w0[j] * we;
        s1 += w1[j] * we;
    }
    qkvsP[(long)k2 * QS + 4096 + hb + d] = pack2(s0, s1);
    if (k2 == 0) {
        float t = 0.f;
        const float* bqh = bq + hb;
        for (int j = 0; j < 256; ++j) t += bqh[j] * wer[j];
        bias5120[4096 + hb + d] = t;
    }
}

// ---------------------------------------------------------------------------
// MFMA GEMM v2 (outT -> grouped gxT layout [g][t][768][4])
// ---------------------------------------------------------------------------
#define TM 128
#define TN 128
#define TK 32
#define BSTR 132

template <typename CT>
__global__ __launch_bounds__(256)
void pgemm_kernel(const bf16* __restrict__ A, const int* __restrict__ arows,
                  const unsigned* __restrict__ Bp, const float* __restrict__ bias,
                  CT* __restrict__ C, int M, int K, int Nc, int relu_out,
                  long astride, int aoff, int colbase, int hslice, int addC, int outT)
{
    __shared__ short    As[TM * TK];
    __shared__ unsigned Bs[(TK / 2) * BSTR];

    const int tid  = threadIdx.x;
    const int lane = tid & 63;
    const int wave = tid >> 6;
    const int wm = wave >> 1, wn = wave & 1;
    const int quad = lane >> 4, c16 = lane & 15;
    const long row0 = (long)blockIdx.y * TM;
    const int  col0 = colbase + blockIdx.x * TN;
    const int  aoff2 = aoff + (hslice ? (col0 & ~255) : 0);

    const int r0 = wave * 32 + (lane >> 2);
    const int cseg = (lane & 3) * 8;
    long gr0 = row0 + r0;      if (gr0 > M - 1) gr0 = M - 1;
    long gr1 = row0 + r0 + 16; if (gr1 > M - 1) gr1 = M - 1;
    long ar0 = arows ? (long)arows[gr0] : gr0;
    long ar1 = arows ? (long)arows[gr1] : gr1;
    const short* Ag0 = (const short*)A + ar0 * astride + aoff2 + cseg;
    const short* Ag1 = (const short*)A + ar1 * astride + aoff2 + cseg;
    short* Ld0 = &As[wave * 1024];
    short* Ld1 = &As[wave * 1024 + 512];

    const int sn2 = tid & 63;
    const int skk = wave * 4;

    f32x4 acc[4][4];
    #pragma unroll
    for (int i = 0; i < 4; ++i)
        #pragma unroll
        for (int j = 0; j < 4; ++j)
            acc[i][j] = (f32x4){0.f, 0.f, 0.f, 0.f};

    for (int k0 = 0; k0 < K; k0 += TK) {
        gld16(Ag0 + k0, Ld0);
        gld16(Ag1 + k0, Ld1);
        #pragma unroll
        for (int i = 0; i < 4; ++i) {
            int kk2 = skk + i;
            *(uint2*)&Bs[kk2 * BSTR + sn2 * 2] =
                *(const uint2*)&Bp[(long)(k0 / 2 + kk2) * Nc + col0 + sn2 * 2];
        }
        __syncthreads();

        short8 af[4];
        U4S8   bfr[4];
        #pragma unroll
        for (int mi = 0; mi < 4; ++mi) {
            int m = wm * 64 + mi * 16 + c16;
            af[mi] = *(const short8*)&As[m * 32 + quad * 8];
        }
        #pragma unroll
        for (int ni = 0; ni < 4; ++ni) {
            int n = wn * 64 + ni * 16 + c16;
            uint4 u;
            u.x = Bs[(quad * 4 + 0) * BSTR + n];
            u.y = Bs[(quad * 4 + 1) * BSTR + n];
            u.z = Bs[(quad * 4 + 2) * BSTR + n];
            u.w = Bs[(quad * 4 + 3) * BSTR + n];
            bfr[ni].u = u;
        }
        #pragma unroll
        for (int mi = 0; mi < 4; ++mi)
            #pragma unroll
            for (int ni = 0; ni < 4; ++ni)
                acc[mi][ni] = __builtin_amdgcn_mfma_f32_16x16x32_bf16(
                    af[mi], bfr[ni].s, acc[mi][ni], 0, 0, 0);
        __syncthreads();
    }

    #pragma unroll
    for (int ni = 0; ni < 4; ++ni) {
        int col = col0 + wn * 64 + ni * 16 + c16;
        float bv = bias ? bias[col] : 0.f;
        #pragma unroll
        for (int mi = 0; mi < 4; ++mi) {
            long row = row0 + wm * 64 + mi * 16 + quad * 4;
            #pragma unroll
            for (int r = 0; r < 4; ++r) {
                if (row + r >= M) continue;
                float v = acc[mi][ni][r] + bv;
                if (addC) v += (float)C[(row + r) * Nc + col];
                if (relu_out) v = fmaxf(v, 0.f);
                if (outT) {
                    long rr = row + r;
                    int t = (int)(rr & 63), b = (int)(rr >> 6);
                    C[(((long)(b >> 2) * 64 + t) * Nc + col) * 4 + (b & 3)] = (CT)v;
                } else {
                    C[(row + r) * Nc + col] = (CT)v;
                }
            }
        }
    }
}

// ---------------------------------------------------------------------------
// Single-kernel CSR
// ---------------------------------------------------------------------------
__global__ __launch_bounds__(1024)
void csr_kernel(const int* __restrict__ edge_index, int b0,
                int* __restrict__ row_start, int* __restrict__ cntg,
                int* __restrict__ elist)
{
    int bl = blockIdx.x;
    int tid = threadIdx.x;
    __shared__ int scnt[1024];
    __shared__ int sscan[1024];

    scnt[tid] = 0;
    __syncthreads();

    const int* dstp = edge_index + (long)(b0 + bl) * 2 * E_ + E_;
    #pragma unroll
    for (int e = tid; e < E_; e += 1024)
        atomicAdd(&scnt[dstp[e]], 1);
    __syncthreads();

    int v = scnt[tid];
    sscan[tid] = v;
    __syncthreads();
    for (int off = 1; off < 1024; off <<= 1) {
        int t = (tid >= off) ? sscan[tid - off] : 0;
        __syncthreads();
        sscan[tid] += t;
        __syncthreads();
    }
    int excl = sscan[tid] - v;
    if (tid < N_) {
        row_start[bl * N_ + tid] = excl;
        cntg[bl * N_ + tid] = v;
    }
    __syncthreads();
    scnt[tid] = excl;
    __syncthreads();

    int* el = elist + (long)bl * E_;
    #pragma unroll
    for (int e = tid; e < E_; e += 1024) {
        int pos = atomicAdd(&scnt[dstp[e]], 1);
        el[pos] = e;
    }
}

// ---------------------------------------------------------------------------
// Fused attention, 2-edge pipeline; qW from qkvs cols 4096..5119
// ---------------------------------------------------------------------------
__device__ __forceinline__ float d2(unsigned a, unsigned b)
{
    return bflo(a) * bflo(b) + bfhi(a) * bfhi(b);
}

__global__ void attn_kernel(const bf16* __restrict__ qkvs,
                            const bf16* __restrict__ embh,
                            const int* __restrict__ edge_tokens, const int* __restrict__ edge_index,
                            const int* __restrict__ row_start, const int* __restrict__ cnt,
                            const int* __restrict__ elist, int b0,
                            bf16* __restrict__ aggb, bf16* __restrict__ xsumb)
{
    int base = blockIdx.x;
    int bl = base / N_;
    int tid = threadIdx.x;
    int l = tid & 63;
    int j0 = tid * 4;
    int jx = l * 4;

    uint2 qq = *(const uint2*)(qkvs + (long)base * QS + j0);
    uint2 ww = *(const uint2*)(qkvs + (long)base * QS + 4096 + j0);

    int start = row_start[base];
    int deg = cnt[base];
    const int* el = elist + (long)bl * E_;
    const int* srcp = edge_index + (long)(b0 + bl) * 2 * E_;
    const int* tokp = edge_tokens + (long)(b0 + bl) * E_;

    float denom = 0.f;
    float v0 = 0.f, v1 = 0.f, v2 = 0.f, v3 = 0.f;
    float x0 = 0.f, x1 = 0.f, x2 = 0.f, x3 = 0.f;

    int t = 0;
    while (t + 1 < deg) {
        int ea = el[start + t], eb2 = el[start + t + 1];
        int sa = srcp[ea], sb = srcp[eb2];
        int ta = tokp[ea], tb = tokp[eb2];
        const bf16* ra = qkvs + (long)(bl * N_ + sa) * QS;
        const bf16* rb = qkvs + (long)(bl * N_ + sb) * QS;
        uint2 ka = *(const uint2*)(ra + 1024 + j0);
        uint2 kb = *(const uint2*)(rb + 1024 + j0);
        uint2 va = *(const uint2*)(ra + 2048 + j0);
        uint2 vb = *(const uint2*)(rb + 2048 + j0);
        uint2 xa = *(const uint2*)(embh + (long)ta * 256 + jx);
        uint2 xb = *(const uint2*)(embh + (long)tb * 256 + jx);

        float s1 = d2(qq.x, ka.x) + d2(qq.y, ka.y) + d2(ww.x, xa.x) + d2(ww.y, xa.y);
        float s2 = d2(qq.x, kb.x) + d2(qq.y, kb.y) + d2(ww.x, xb.x) + d2(ww.y, xb.y);
        s1 += __shfl_xor(s1, 32);  s2 += __shfl_xor(s2, 32);
        s1 += __shfl_xor(s1, 16);  s2 += __shfl_xor(s2, 16);
        s1 += __shfl_xor(s1, 8);   s2 += __shfl_xor(s2, 8);
        s1 += __shfl_xor(s1, 4);   s2 += __shfl_xor(s2, 4);
        s1 += __shfl_xor(s1, 2);   s2 += __shfl_xor(s2, 2);
        s1 += __shfl_xor(s1, 1);   s2 += __shfl_xor(s2, 1);
        float exa = __builtin_amdgcn_exp2f(s1 * (SCALE_ * LOG2E));
        float exb = __builtin_amdgcn_exp2f(s2 * (SCALE_ * LOG2E));

        denom += exa + exb;
        v0 += exa * bflo(va.x) + exb * bflo(vb.x);
        v1 += exa * bfhi(va.x) + exb * bfhi(vb.x);
        v2 += exa * bflo(va.y) + exb * bflo(vb.y);
        v3 += exa * bfhi(va.y) + exb * bfhi(vb.y);
        x0 += exa * bflo(xa.x) + exb * bflo(xb.x);
        x1 += exa * bfhi(xa.x) + exb * bfhi(xb.x);
        x2 += exa * bflo(xa.y) + exb * bflo(xb.y);
        x3 += exa * bfhi(xa.y) + exb * bfhi(xb.y);
        t += 2;
    }
    if (t < deg) {
        int ea = el[start + t];
        int sa = srcp[ea], ta = tokp[ea];
        const bf16* ra = qkvs + (long)(bl * N_ + sa) * QS;
        uint2 ka = *(const uint2*)(ra + 1024 + j0);
        uint2 va = *(const uint2*)(ra + 2048 + j0);
        uint2 xa = *(const uint2*)(embh + (long)ta * 256 + jx);
        float s1 = d2(qq.x, ka.x) + d2(qq.y, ka.y) + d2(ww.x, xa.x) + d2(ww.y, xa.y);
        s1 += __shfl_xor(s1, 32);
        s1 += __shfl_xor(s1, 16);
        s1 += __shfl_xor(s1, 8);
        s1 += __shfl_xor(s1, 4);
        s1 += __shfl_xor(s1, 2);
        s1 += __shfl_xor(s1, 1);
        float exa = __builtin_amdgcn_exp2f(s1 * (SCALE_ * LOG2E));
        denom += exa;
        v0 += exa * bflo(va.x); v1 += exa * bfhi(va.x);
        v2 += exa * bflo(va.y); v3 += exa * bfhi(va.y);
        x0 += exa * bflo(xa.x); x1 += exa * bfhi(xa.x);
        x2 += exa * bflo(xa.y); x3 += exa * bfhi(xa.y);
    }

    float invd = (deg > 0) ? 1.f / denom : 0.f;
    uint2 sk = *(const uint2*)(qkvs + (long)base * QS + 3072 + j0);
    unsigned o0 = pack2(bflo(sk.x) + v0 * invd, bfhi(sk.x) + v1 * invd);
    unsigned o1 = pack2(bflo(sk.y) + v2 * invd, bfhi(sk.y) + v3 * invd);
    *(uint2*)(aggb + (long)base * HD_ + j0) = make_uint2(o0, o1);
    *(uint2*)(xsumb + (long)base * HD_ + j0) =
        make_uint2(pack2(x0 * invd, x1 * invd), pack2(x2 * invd, x3 * invd));
}

// ---------------------------------------------------------------------------
// mixed embed, inv rows only -> bf16 (aa gather folded into score)
// ---------------------------------------------------------------------------
__global__ void mixed_inv_kernel(const bf16* __restrict__ embh,
                                 const int* __restrict__ inv_token,
                                 const int* __restrict__ inv_node,
                                 const bf16* __restrict__ graph_repr,
                                 bf16* __restrict__ mixed_inv)
{
    int r = blockIdx.x;
    int b = r / L_;
    int d = threadIdx.x;
    float v = (float)embh[(long)inv_token[r] * D_ + d] +
              (float)graph_repr[((long)b * N_ + inv_node[r]) * D_ + d];
    mixed_inv[(long)r * D_ + d] = __float2bfloat16(v);
}

// ---------------------------------------------------------------------------
// GRU via MFMA, 4 blocks x 4 batches.  hB compacted to 4 rows: all lanes read
// row (c16>>2) -> same-address broadcast within (c16>>2,quad) groups; garbage
// in unused A-rows is harmless (their D-rows never extracted).  LDS traffic
// per step drops ~8x (was the round-15 bottleneck: 131072 conflicts/dispatch).
// ---------------------------------------------------------------------------
__global__ __launch_bounds__(1024)
void gru_kernel(const bf16* __restrict__ gxT, const short8* __restrict__ WhhP,
                const float* __restrict__ b_hh, float* __restrict__ inv_out)
{
    __shared__ short hB[2][4 * 264];

    const int tid = threadIdx.x;
    const int lane = tid & 63;
    const int wave = tid >> 6;
    const int quad = lane >> 4, c16 = lane & 15;
    const int n0 = wave * 16 + c16;
    const int bb = blockIdx.x * 4 + quad;
    const int mrow = c16 >> 2;              // compacted hB row for A-frag

    for (int i = tid; i < 2 * 4 * 264; i += 1024) ((short*)hB)[i] = 0;

    short8 wfr[8], wfz[8], wfn[8];
    #pragma unroll
    for (int tk = 0; tk < 8; ++tk) {
        wfr[tk] = WhhP[((0 * 16 + wave) * 8 + tk) * 64 + lane];
        wfz[tk] = WhhP[((1 * 16 + wave) * 8 + tk) * 64 + lane];
        wfn[tk] = WhhP[((2 * 16 + wave) * 8 + tk) * 64 + lane];
    }
    float bhr = b_hh[0 * 256 + n0];
    float bhz = b_hh[1 * 256 + n0];
    float bhn = b_hh[2 * 256 + n0];

    float myh = 0.f;

    const unsigned short* g_r = (const unsigned short*)gxT +
        ((long)blockIdx.x * 64 * 768 + n0) * 4 + quad;
    const unsigned short* g_z = g_r + 256 * 4;
    const unsigned short* g_n = g_r + 512 * 4;

    unsigned short pr = g_r[0], pz = g_z[0], pn = g_n[0];

    __syncthreads();

    int p = 0;
    for (int t = 0; t < L_; ++t) {
        float xr = __uint_as_float((unsigned)pr << 16);
        float xz = __uint_as_float((unsigned)pz << 16);
        float xn = __uint_as_float((unsigned)pn << 16);
        long noff = (long)((t + 1 < L_) ? t + 1 : t) * 3072;
        pr = g_r[noff]; pz = g_z[noff]; pn = g_n[noff];

        // A-frag m = c16 reads compacted row c16>>2: effective A row m holds
        // h of batch m>>2; extracted D rows m = quad*4 (r=0) -> batch quad. OK.
        f32x4 ar = (f32x4){bhr, bhr, bhr, bhr};
        f32x4 az = (f32x4){bhz, bhz, bhz, bhz};
        f32x4 an = (f32x4){bhn, bhn, bhn, bhn};
        const short* hp = &hB[p][0];
        #pragma unroll
        for (int tk = 0; tk < 8; ++tk) {
            short8 a = *(const short8*)&hp[mrow * 264 + tk * 32 + quad * 8];
            ar = __builtin_amdgcn_mfma_f32_16x16x32_bf16(a, wfr[tk], ar, 0, 0, 0);
            az = __builtin_amdgcn_mfma_f32_16x16x32_bf16(a, wfz[tk], az, 0, 0, 0);
            an = __builtin_amdgcn_mfma_f32_16x16x32_bf16(a, wfn[tk], an, 0, 0, 0);
        }

        float rr = fsigm(xr + ar[0]);
        float zz = fsigm(xz + az[0]);
        float cc = ftanh(xn + rr * an[0]);
        myh = (1.f - zz) * cc + zz * myh;
        hB[p ^ 1][quad * 264 + n0] = (short)rne1(myh);
        p ^= 1;
        __syncthreads();
    }

    inv_out[(long)bb * 256 + n0] = myh;
}

// ---------------------------------------------------------------------------
// fused score: per-batch block computes u = Wab + Wap@inv, s0 = bab + bap·inv,
// then 128 action scores with inline aa_emb gather (embh[tok] + graph_repr).
// grid = B_ blocks x 256 threads.
// ---------------------------------------------------------------------------
__global__ __launch_bounds__(256)
void score_kernel(const float* __restrict__ Wap, const float* __restrict__ Wab,
                  const float* __restrict__ bap, const float* __restrict__ bab,
                  const float* __restrict__ inv,
                  const bf16* __restrict__ embh, const bf16* __restrict__ graph_repr,
                  const int* __restrict__ aa_token, const int* __restrict__ aa_node,
                  const float* __restrict__ mask, float* __restrict__ out)
{
    int b = blockIdx.x, tid = threadIdx.x;
    __shared__ float iv[256];
    __shared__ float u[256];
    __shared__ float s0s;
    iv[tid] = inv[(long)b * 256 + tid];
    __syncthreads();
    float s = Wab[tid];
    const float* wr = Wap + (long)tid * 256;
    #pragma unroll 8
    for (int o = 0; o < 256; ++o) s += wr[o] * iv[o];
    u[tid] = s;
    if (tid == 0) {
        float t = bab[0];
        for (int o = 0; o < 256; ++o) t += bap[o] * iv[o];
        s0s = t;
    }
    __syncthreads();

    int wv = tid >> 6, l = tid & 63;
    for (int a = wv; a < A_; a += 4) {
        int r = b * A_ + a;
        int tok = aa_token[r], nd = aa_node[r];
        const bf16* ep = embh + (long)tok * 256;
        const bf16* gp = graph_repr + ((long)b * N_ + nd) * 256;
        float acc = 0.f;
        #pragma unroll
        for (int d = l * 4; d < (l + 1) * 4; ++d)
            acc += ((float)ep[d] + (float)gp[d]) * u[d];
        #pragma unroll
        for (int off = 32; off; off >>= 1) acc += __shfl_down(acc, off);
        if (l == 0) {
            float lm = logf(mask[r]);
            const float MN = -3.4028234663852886e38f;
            if (!(lm >= MN)) lm = MN;
            out[r] = acc + s0s + lm;
        }
    }
}

// ---------------------------------------------------------------------------
// host
// ---------------------------------------------------------------------------
static inline size_t align256(size_t x) { return (x + 255) & ~(size_t)255; }

template <typename CT>
static void launch_pgemm(const bf16* A, const int* arows, const unsigned* Bp,
                         const float* bias, CT* C, int M, int K, int Nc, int relu,
                         long astride, int aoff, int colbase, int hslice, int addC,
                         int outT, int ncols, hipStream_t s)
{
    dim3 grid(ncols / TN, (M + TM - 1) / TM);
    pgemm_kernel<CT><<<grid, 256, 0, s>>>(A, arows, Bp, bias, C, M, K, Nc, relu,
                                          astride, aoff, colbase, hslice, addC, outT);
}

extern "C" void kernel_launch(void* const* d_in, const int* in_sizes, int n_in,
                              void* d_out, int out_size, void* d_ws, size_t ws_size,
                              hipStream_t stream)
{
    const int* node_tokens = (const int*)d_in[0];
    const int* edge_tokens = (const int*)d_in[1];
    const int* edge_index  = (const int*)d_in[2];
    const int* inv_token   = (const int*)d_in[3];
    const int* inv_node    = (const int*)d_in[4];
    const int* aa_token    = (const int*)d_in[5];
    const int* aa_node     = (const int*)d_in[6];
    const float* action_mask = (const float*)d_in[7];
    const float* emb   = (const float*)d_in[8];
    const float* Wq    = (const float*)d_in[9];
    const float* bq    = (const float*)d_in[10];
    const float* Wk    = (const float*)d_in[11];
    const float* bk    = (const float*)d_in[12];
    const float* Wv    = (const float*)d_in[13];
    const float* bv    = (const float*)d_in[14];
    const float* We    = (const float*)d_in[15];
    const float* Wskip = (const float*)d_in[16];
    const float* bskip = (const float*)d_in[17];
    const float* W1    = (const float*)d_in[18];
    const float* b1    = (const float*)d_in[19];
    const float* Wp    = (const float*)d_in[20];
    const float* bp    = (const float*)d_in[21];
    const float* W_ih  = (const float*)d_in[22];
    const float* W_hh  = (const float*)d_in[23];
    const float* b_ih  = (const float*)d_in[24];
    const float* b_hh  = (const float*)d_in[25];
    const float* Wab   = (const float*)d_in[26];
    const float* bab   = (const float*)d_in[27];
    const float* Wap   = (const float*)d_in[28];
    const float* bap   = (const float*)d_in[29];
    (void)in_sizes; (void)n_in; (void)out_size;

    char* base = (char*)d_ws;
    size_t off = 0;
    auto alloc = [&](size_t bytes) -> char* {
        char* p = base + off;
        off = align256(off + bytes);
        return p;
    };

    // persistent buffers
    const long VD = 50000L * 256;
    bf16*  embh       = (bf16*)alloc(VD * 2);
    bf16*  graph_repr = (bf16*)alloc((size_t)B_ * N_ * D_ * 2);
    bf16*  mixed_inv  = (bf16*)alloc((size_t)B_ * L_ * D_ * 2);
    bf16*  inv_h      = (bf16*)alloc((size_t)B_ * L_ * D_ * 2);
    bf16*  gxT        = (bf16*)alloc((size_t)B_ * L_ * 768 * 2);
    float* inv_out    = (float*)alloc((size_t)B_ * 256 * 4);
    unsigned* qkvsP   = (unsigned*)alloc((size_t)128 * QS * 4);
    unsigned* WeP     = (unsigned*)alloc((size_t)128 * 1024 * 4);
    unsigned* W1P     = (unsigned*)alloc((size_t)512 * 256 * 4);
    unsigned* WpP     = (unsigned*)alloc((size_t)128 * 256 * 4);
    unsigned* WihP    = (unsigned*)alloc((size_t)128 * 768 * 4);
    short8* WhhP      = (short8*)alloc((size_t)24576 * 16);
    float* bias5120   = (float*)alloc(QS * 4);
    size_t persist = off;

    // batch-chunk size
    int c = 16;
    while (c > 1) {
        size_t cN = (size_t)c * N_, cEs = (size_t)c * E_;
        size_t chunk = align256(cN * QS * 2)
                     + align256(cN * HD_ * 2)
                     + align256(cN * HD_ * 2)
                     + 2 * align256(cN * 4)
                     + align256(cEs * 4);
        if (persist + chunk <= ws_size) break;
        c >>= 1;
    }
    int cN = c * N_, cE = c * E_;

    bf16*  qkvs  = (bf16*)alloc((size_t)cN * QS * 2);
    bf16*  aggb  = (bf16*)alloc((size_t)cN * HD_ * 2);
    bf16*  xsumb = (bf16*)alloc((size_t)cN * HD_ * 2);
    int*   cnt   = (int*)alloc((size_t)cN * 4);
    int*   rstart= (int*)alloc((size_t)cN * 4);
    int*   elist = (int*)alloc((size_t)cE * 4);

    // ---- pre-pass ----
    convemb_kernel<<<(int)((VD / 4 + 255) / 256), 256, 0, stream>>>(emb, embh, VD / 4);
    pack_all_kernel<<<(PACK_ALL_TOT + 255) / 256, 256, 0, stream>>>(
        Wq, Wk, Wv, Wskip, We, W1, Wp, W_ih, W_hh, bq, bk, bv, bskip,
        qkvsP, WeP, W1P, WpP, WihP, WhhP, bias5120);
    wqe_kernel<<<512, 256, 0, stream>>>(Wq, We, bq, qkvsP, bias5120);

    for (int b0 = 0; b0 < B_; b0 += c) {
        csr_kernel<<<c, 1024, 0, stream>>>(edge_index, b0, rstart, cnt, elist);
        launch_pgemm<bf16>(embh, node_tokens + (long)b0 * N_, qkvsP, bias5120, qkvs,
                           cN, D_, QS, 0, 256, 0, 0, 0, 0, 0, QS, stream);
        attn_kernel<<<cN, 256, 0, stream>>>(qkvs, embh, edge_tokens, edge_index,
                                            rstart, cnt, elist, b0, aggb, xsumb);
        launch_pgemm<bf16>(xsumb, nullptr, WeP, nullptr, aggb,
                           cN, 256, 1024, 1, 1024, 0, 0, 1, 1, 0, 1024, stream);
        launch_pgemm<bf16>(aggb, nullptr, W1P, b1,
                           graph_repr + (long)b0 * N_ * D_,
                           cN, HD_, D_, 1, 1024, 0, 0, 0, 0, 0, 256, stream);
    }

    // invariant path
    mixed_inv_kernel<<<B_ * L_, 256, 0, stream>>>(embh, inv_token, inv_node,
                                                  graph_repr, mixed_inv);
    launch_pgemm<bf16>(mixed_inv, nullptr, WpP, bp, inv_h,
                       B_ * L_, D_, 256, 1, 256, 0, 0, 0, 0, 0, 256, stream);
    launch_pgemm<bf16>(inv_h, nullptr, WihP, b_ih, gxT,
                       B_ * L_, 256, 768, 0, 256, 0, 0, 0, 0, 1, 768, stream);
    gru_kernel<<<4, 1024, 0, stream>>>(gxT, WhhP, b_hh, inv_out);

    // action path (uprep + aa gather folded into score)
    score_kernel<<<B_, 256, 0, stream>>>(Wap, Wab, bap, bab, inv_out, embh,
                                         graph_repr, aa_token, aa_node,
                                         action_mask, (float*)d_out);
}

// Round 17
// 755.691 us; speedup vs baseline: 1.0431x; 1.0431x over previous
//
#include <hip/hip_runtime.h>
#include <hip/hip_bf16.h>
#include <float.h>
#include <math.h>

typedef __hip_bfloat16 bf16;

#define B_ 16
#define N_ 1000
#define E_ 4000
#define L_ 64
#define A_ 128
#define D_ 256
#define H_ 4
#define HD_ 1024
#define SCALE_ 0.0625f
#define QS 5120   // fused projection stride: q|k|v|skip|qW

typedef __attribute__((ext_vector_type(8))) short short8;
typedef __attribute__((ext_vector_type(4))) float f32x4;

union U4S8 { uint4 u; short8 s; };

__device__ __forceinline__ unsigned short f2bf(float f) {
    bf16 h = __float2bfloat16(f);
    return *reinterpret_cast<unsigned short*>(&h);
}
__device__ __forceinline__ unsigned pack2(float a, float b) {
    return (unsigned)f2bf(a) | ((unsigned)f2bf(b) << 16);
}
__device__ __forceinline__ unsigned short rne1(float a) {
    unsigned ua = __float_as_uint(a);
    ua += 0x7fff + ((ua >> 16) & 1);
    return (unsigned short)(ua >> 16);
}
__device__ __forceinline__ float bflo(unsigned u) { return __uint_as_float(u << 16); }
__device__ __forceinline__ float bfhi(unsigned u) { return __uint_as_float(u & 0xffff0000u); }

#define LOG2E 1.4426950408889634f
__device__ __forceinline__ float fsigm(float x) {
    return __builtin_amdgcn_rcpf(1.f + __builtin_amdgcn_exp2f(-LOG2E * x));
}
__device__ __forceinline__ float ftanh(float x) {
    return 1.f - 2.f * __builtin_amdgcn_rcpf(1.f + __builtin_amdgcn_exp2f(2.f * LOG2E * x));
}

// async global->LDS, 16B per lane
typedef const __attribute__((address_space(1))) unsigned int* gas_t;
typedef __attribute__((address_space(3))) unsigned int* las_t;
__device__ __forceinline__ void gld16(const void* g, void* l) {
    __builtin_amdgcn_global_load_lds((gas_t)g, (las_t)l, 16, 0, 0);
}

// ---------------------------------------------------------------------------
// Pre-pass: emb->bf16
// ---------------------------------------------------------------------------
__global__ void convemb_kernel(const float* __restrict__ src, bf16* __restrict__ dst, long n4)
{
    long i = (long)blockIdx.x * 256 + threadIdx.x;
    if (i >= n4) return;
    float4 v = *(const float4*)(src + i * 4);
    *(uint2*)(dst + i * 4) = make_uint2(pack2(v.x, v.y), pack2(v.z, v.w));
}

// ---------------------------------------------------------------------------
// Fused weight-pack pre-pass (qkvsP has stride QS; cols 4096.. filled by wqe)
// ---------------------------------------------------------------------------
__global__ void pack_all_kernel(const float* __restrict__ Wq, const float* __restrict__ Wk,
                                const float* __restrict__ Wv, const float* __restrict__ Wskip,
                                const float* __restrict__ We, const float* __restrict__ W1,
                                const float* __restrict__ Wp, const float* __restrict__ W_ih,
                                const float* __restrict__ W_hh,
                                const float* __restrict__ bq, const float* __restrict__ bk,
                                const float* __restrict__ bv, const float* __restrict__ bskip,
                                unsigned* __restrict__ qkvsP, unsigned* __restrict__ WeP,
                                unsigned* __restrict__ W1P, unsigned* __restrict__ WpP,
                                unsigned* __restrict__ WihP,
                                short8* __restrict__ WhhP, float* __restrict__ bias5120)
{
    int i = blockIdx.x * 256 + threadIdx.x;
    if (i < 524288) {                       // qkvsP cols 0..4095: 128 k2 x 4096
        int k2 = i >> 12, n = i & 4095;
        const float* s = (n < 1024) ? Wq : (n < 2048) ? Wk : (n < 3072) ? Wv : Wskip;
        int col = n & 1023;
        qkvsP[(long)k2 * QS + n] =
            pack2(s[(long)(2 * k2) * 1024 + col], s[(long)(2 * k2 + 1) * 1024 + col]);
        return;
    }
    i -= 524288;
    if (i < 131072) {                       // WeP: 128 x 1024
        int k2 = i >> 10, n = i & 1023;
        WeP[i] = pack2(We[(long)(2 * k2) * 1024 + n], We[(long)(2 * k2 + 1) * 1024 + n]);
        return;
    }
    i -= 131072;
    if (i < 131072) {                       // W1P: 512 k2 x 256
        int k2 = i >> 8, n = i & 255;
        W1P[i] = pack2(W1[(long)(2 * k2) * 256 + n], W1[(long)(2 * k2 + 1) * 256 + n]);
        return;
    }
    i -= 131072;
    if (i < 32768) {                        // WpP: 128 x 256
        int k2 = i >> 8, n = i & 255;
        WpP[i] = pack2(Wp[(long)(2 * k2) * 256 + n], Wp[(long)(2 * k2 + 1) * 256 + n]);
        return;
    }
    i -= 32768;
    if (i < 98304) {                        // WihP (transposed src [768,256]): 128 k2 x 768
        int k2 = i / 768, n = i % 768;
        WihP[i] = pack2(W_ih[(long)n * 256 + 2 * k2], W_ih[(long)n * 256 + 2 * k2 + 1]);
        return;
    }
    i -= 98304;
    if (i < 24576) {                        // WhhP MFMA B-frag stream (48 tiles)
        int lane = i & 63, tk = (i >> 6) & 7, tile = i >> 9;
        int n = tile * 16 + (lane & 15);
        const float* wp = W_hh + (long)n * 256 + tk * 32 + (lane >> 4) * 8;
        float4 w0 = *(const float4*)wp;
        float4 w1 = *(const float4*)(wp + 4);
        U4S8 u;
        u.u = make_uint4(pack2(w0.x, w0.y), pack2(w0.z, w0.w),
                         pack2(w1.x, w1.y), pack2(w1.z, w1.w));
        WhhP[i] = u.s;
        return;
    }
    i -= 24576;
    if (i < 4096) {                         // bias cols 0..4095
        int q = i >> 10, c = i & 1023;
        bias5120[i] = ((q == 0) ? bq : (q == 1) ? bk : (q == 2) ? bv : bskip)[c];
    }
}
#define PACK_ALL_TOT (524288 + 131072 + 131072 + 32768 + 98304 + 24576 + 4096)

// ---------------------------------------------------------------------------
// Wqe = Wq_h @ We_h^T
// ---------------------------------------------------------------------------
__global__ __launch_bounds__(256)
void wqe_kernel(const float* __restrict__ Wq, const float* __restrict__ We,
                const float* __restrict__ bq,
                unsigned* __restrict__ qkvsP, float* __restrict__ bias5120)
{
    int k2 = blockIdx.x >> 2;
    int h  = blockIdx.x & 3;
    int d  = threadIdx.x;
    int hb = h * 256;
    __shared__ float w0[256], w1[256];
    w0[d] = Wq[(long)(2 * k2) * 1024 + hb + d];
    w1[d] = Wq[(long)(2 * k2 + 1) * 1024 + hb + d];
    __syncthreads();
    const float* wer = We + (long)d * 1024 + hb;
    float s0 = 0.f, s1 = 0.f;
    #pragma unroll 8
    for (int j = 0; j < 256; ++j) {
        float we = wer[j];
        s0 += w0[j] * we;
        s1 += w1[j] * we;
    }
    qkvsP[(long)k2 * QS + 4096 + hb + d] = pack2(s0, s1);
    if (k2 == 0) {
        float t = 0.f;
        const float* bqh = bq + hb;
        for (int j = 0; j < 256; ++j) t += bqh[j] * wer[j];
        bias5120[4096 + hb + d] = t;
    }
}

// ---------------------------------------------------------------------------
// MFMA GEMM v2 (outT -> grouped gxT layout [g][t][768][4])
// ---------------------------------------------------------------------------
#define TM 128
#define TN 128
#define TK 32
#define BSTR 132

template <typename CT>
__global__ __launch_bounds__(256)
void pgemm_kernel(const bf16* __restrict__ A, const int* __restrict__ arows,
                  const unsigned* __restrict__ Bp, const float* __restrict__ bias,
                  CT* __restrict__ C, int M, int K, int Nc, int relu_out,
                  long astride, int aoff, int colbase, int hslice, int addC, int outT)
{
    __shared__ short    As[TM * TK];
    __shared__ unsigned Bs[(TK / 2) * BSTR];

    const int tid  = threadIdx.x;
    const int lane = tid & 63;
    const int wave = tid >> 6;
    const int wm = wave >> 1, wn = wave & 1;
    const int quad = lane >> 4, c16 = lane & 15;
    const long row0 = (long)blockIdx.y * TM;
    const int  col0 = colbase + blockIdx.x * TN;
    const int  aoff2 = aoff + (hslice ? (col0 & ~255) : 0);

    const int r0 = wave * 32 + (lane >> 2);
    const int cseg = (lane & 3) * 8;
    long gr0 = row0 + r0;      if (gr0 > M - 1) gr0 = M - 1;
    long gr1 = row0 + r0 + 16; if (gr1 > M - 1) gr1 = M - 1;
    long ar0 = arows ? (long)arows[gr0] : gr0;
    long ar1 = arows ? (long)arows[gr1] : gr1;
    const short* Ag0 = (const short*)A + ar0 * astride + aoff2 + cseg;
    const short* Ag1 = (const short*)A + ar1 * astride + aoff2 + cseg;
    short* Ld0 = &As[wave * 1024];
    short* Ld1 = &As[wave * 1024 + 512];

    const int sn2 = tid & 63;
    const int skk = wave * 4;

    f32x4 acc[4][4];
    #pragma unroll
    for (int i = 0; i < 4; ++i)
        #pragma unroll
        for (int j = 0; j < 4; ++j)
            acc[i][j] = (f32x4){0.f, 0.f, 0.f, 0.f};

    for (int k0 = 0; k0 < K; k0 += TK) {
        gld16(Ag0 + k0, Ld0);
        gld16(Ag1 + k0, Ld1);
        #pragma unroll
        for (int i = 0; i < 4; ++i) {
            int kk2 = skk + i;
            *(uint2*)&Bs[kk2 * BSTR + sn2 * 2] =
                *(const uint2*)&Bp[(long)(k0 / 2 + kk2) * Nc + col0 + sn2 * 2];
        }
        __syncthreads();

        short8 af[4];
        U4S8   bfr[4];
        #pragma unroll
        for (int mi = 0; mi < 4; ++mi) {
            int m = wm * 64 + mi * 16 + c16;
            af[mi] = *(const short8*)&As[m * 32 + quad * 8];
        }
        #pragma unroll
        for (int ni = 0; ni < 4; ++ni) {
            int n = wn * 64 + ni * 16 + c16;
            uint4 u;
            u.x = Bs[(quad * 4 + 0) * BSTR + n];
            u.y = Bs[(quad * 4 + 1) * BSTR + n];
            u.z = Bs[(quad * 4 + 2) * BSTR + n];
            u.w = Bs[(quad * 4 + 3) * BSTR + n];
            bfr[ni].u = u;
        }
        #pragma unroll
        for (int mi = 0; mi < 4; ++mi)
            #pragma unroll
            for (int ni = 0; ni < 4; ++ni)
                acc[mi][ni] = __builtin_amdgcn_mfma_f32_16x16x32_bf16(
                    af[mi], bfr[ni].s, acc[mi][ni], 0, 0, 0);
        __syncthreads();
    }

    #pragma unroll
    for (int ni = 0; ni < 4; ++ni) {
        int col = col0 + wn * 64 + ni * 16 + c16;
        float bv = bias ? bias[col] : 0.f;
        #pragma unroll
        for (int mi = 0; mi < 4; ++mi) {
            long row = row0 + wm * 64 + mi * 16 + quad * 4;
            #pragma unroll
            for (int r = 0; r < 4; ++r) {
                if (row + r >= M) continue;
                float v = acc[mi][ni][r] + bv;
                if (addC) v += (float)C[(row + r) * Nc + col];
                if (relu_out) v = fmaxf(v, 0.f);
                if (outT) {
                    long rr = row + r;
                    int t = (int)(rr & 63), b = (int)(rr >> 6);
                    C[(((long)(b >> 2) * 64 + t) * Nc + col) * 4 + (b & 3)] = (CT)v;
                } else {
                    C[(row + r) * Nc + col] = (CT)v;
                }
            }
        }
    }
}

// ---------------------------------------------------------------------------
// Single-kernel CSR
// ---------------------------------------------------------------------------
__global__ __launch_bounds__(1024)
void csr_kernel(const int* __restrict__ edge_index, int b0,
                int* __restrict__ row_start, int* __restrict__ cntg,
                int* __restrict__ elist)
{
    int bl = blockIdx.x;
    int tid = threadIdx.x;
    __shared__ int scnt[1024];
    __shared__ int sscan[1024];

    scnt[tid] = 0;
    __syncthreads();

    const int* dstp = edge_index + (long)(b0 + bl) * 2 * E_ + E_;
    #pragma unroll
    for (int e = tid; e < E_; e += 1024)
        atomicAdd(&scnt[dstp[e]], 1);
    __syncthreads();

    int v = scnt[tid];
    sscan[tid] = v;
    __syncthreads();
    for (int off = 1; off < 1024; off <<= 1) {
        int t = (tid >= off) ? sscan[tid - off] : 0;
        __syncthreads();
        sscan[tid] += t;
        __syncthreads();
    }
    int excl = sscan[tid] - v;
    if (tid < N_) {
        row_start[bl * N_ + tid] = excl;
        cntg[bl * N_ + tid] = v;
    }
    __syncthreads();
    scnt[tid] = excl;
    __syncthreads();

    int* el = elist + (long)bl * E_;
    #pragma unroll
    for (int e = tid; e < E_; e += 1024) {
        int pos = atomicAdd(&scnt[dstp[e]], 1);
        el[pos] = e;
    }
}

// ---------------------------------------------------------------------------
// Fused attention, 2-edge pipeline; qW from qkvs cols 4096..5119
// ---------------------------------------------------------------------------
__device__ __forceinline__ float d2(unsigned a, unsigned b)
{
    return bflo(a) * bflo(b) + bfhi(a) * bfhi(b);
}

__global__ void attn_kernel(const bf16* __restrict__ qkvs,
                            const bf16* __restrict__ embh,
                            const int* __restrict__ edge_tokens, const int* __restrict__ edge_index,
                            const int* __restrict__ row_start, const int* __restrict__ cnt,
                            const int* __restrict__ elist, int b0,
                            bf16* __restrict__ aggb, bf16* __restrict__ xsumb)
{
    int base = blockIdx.x;
    int bl = base / N_;
    int tid = threadIdx.x;
    int l = tid & 63;
    int j0 = tid * 4;
    int jx = l * 4;

    uint2 qq = *(const uint2*)(qkvs + (long)base * QS + j0);
    uint2 ww = *(const uint2*)(qkvs + (long)base * QS + 4096 + j0);

    int start = row_start[base];
    int deg = cnt[base];
    const int* el = elist + (long)bl * E_;
    const int* srcp = edge_index + (long)(b0 + bl) * 2 * E_;
    const int* tokp = edge_tokens + (long)(b0 + bl) * E_;

    float denom = 0.f;
    float v0 = 0.f, v1 = 0.f, v2 = 0.f, v3 = 0.f;
    float x0 = 0.f, x1 = 0.f, x2 = 0.f, x3 = 0.f;

    int t = 0;
    while (t + 1 < deg) {
        int ea = el[start + t], eb2 = el[start + t + 1];
        int sa = srcp[ea], sb = srcp[eb2];
        int ta = tokp[ea], tb = tokp[eb2];
        const bf16* ra = qkvs + (long)(bl * N_ + sa) * QS;
        const bf16* rb = qkvs + (long)(bl * N_ + sb) * QS;
        uint2 ka = *(const uint2*)(ra + 1024 + j0);
        uint2 kb = *(const uint2*)(rb + 1024 + j0);
        uint2 va = *(const uint2*)(ra + 2048 + j0);
        uint2 vb = *(const uint2*)(rb + 2048 + j0);
        uint2 xa = *(const uint2*)(embh + (long)ta * 256 + jx);
        uint2 xb = *(const uint2*)(embh + (long)tb * 256 + jx);

        float s1 = d2(qq.x, ka.x) + d2(qq.y, ka.y) + d2(ww.x, xa.x) + d2(ww.y, xa.y);
        float s2 = d2(qq.x, kb.x) + d2(qq.y, kb.y) + d2(ww.x, xb.x) + d2(ww.y, xb.y);
        s1 += __shfl_xor(s1, 32);  s2 += __shfl_xor(s2, 32);
        s1 += __shfl_xor(s1, 16);  s2 += __shfl_xor(s2, 16);
        s1 += __shfl_xor(s1, 8);   s2 += __shfl_xor(s2, 8);
        s1 += __shfl_xor(s1, 4);   s2 += __shfl_xor(s2, 4);
        s1 += __shfl_xor(s1, 2);   s2 += __shfl_xor(s2, 2);
        s1 += __shfl_xor(s1, 1);   s2 += __shfl_xor(s2, 1);
        float exa = __builtin_amdgcn_exp2f(s1 * (SCALE_ * LOG2E));
        float exb = __builtin_amdgcn_exp2f(s2 * (SCALE_ * LOG2E));

        denom += exa + exb;
        v0 += exa * bflo(va.x) + exb * bflo(vb.x);
        v1 += exa * bfhi(va.x) + exb * bfhi(vb.x);
        v2 += exa * bflo(va.y) + exb * bflo(vb.y);
        v3 += exa * bfhi(va.y) + exb * bfhi(vb.y);
        x0 += exa * bflo(xa.x) + exb * bflo(xb.x);
        x1 += exa * bfhi(xa.x) + exb * bfhi(xb.x);
        x2 += exa * bflo(xa.y) + exb * bflo(xb.y);
        x3 += exa * bfhi(xa.y) + exb * bfhi(xb.y);
        t += 2;
    }
    if (t < deg) {
        int ea = el[start + t];
        int sa = srcp[ea], ta = tokp[ea];
        const bf16* ra = qkvs + (long)(bl * N_ + sa) * QS;
        uint2 ka = *(const uint2*)(ra + 1024 + j0);
        uint2 va = *(const uint2*)(ra + 2048 + j0);
        uint2 xa = *(const uint2*)(embh + (long)ta * 256 + jx);
        float s1 = d2(qq.x, ka.x) + d2(qq.y, ka.y) + d2(ww.x, xa.x) + d2(ww.y, xa.y);
        s1 += __shfl_xor(s1, 32);
        s1 += __shfl_xor(s1, 16);
        s1 += __shfl_xor(s1, 8);
        s1 += __shfl_xor(s1, 4);
        s1 += __shfl_xor(s1, 2);
        s1 += __shfl_xor(s1, 1);
        float exa = __builtin_amdgcn_exp2f(s1 * (SCALE_ * LOG2E));
        denom += exa;
        v0 += exa * bflo(va.x); v1 += exa * bfhi(va.x);
        v2 += exa * bflo(va.y); v3 += exa * bfhi(va.y);
        x0 += exa * bflo(xa.x); x1 += exa * bfhi(xa.x);
        x2 += exa * bflo(xa.y); x3 += exa * bfhi(xa.y);
    }

    float invd = (deg > 0) ? 1.f / denom : 0.f;
    uint2 sk = *(const uint2*)(qkvs + (long)base * QS + 3072 + j0);
    unsigned o0 = pack2(bflo(sk.x) + v0 * invd, bfhi(sk.x) + v1 * invd);
    unsigned o1 = pack2(bflo(sk.y) + v2 * invd, bfhi(sk.y) + v3 * invd);
    *(uint2*)(aggb + (long)base * HD_ + j0) = make_uint2(o0, o1);
    *(uint2*)(xsumb + (long)base * HD_ + j0) =
        make_uint2(pack2(x0 * invd, x1 * invd), pack2(x2 * invd, x3 * invd));
}

// ---------------------------------------------------------------------------
// fused mixed embed (inv rows then aa rows) -> bf16
// ---------------------------------------------------------------------------
__global__ void mixed2_kernel(const bf16* __restrict__ embh,
                              const int* __restrict__ inv_token, const int* __restrict__ inv_node,
                              const int* __restrict__ aa_token, const int* __restrict__ aa_node,
                              const bf16* __restrict__ graph_repr,
                              bf16* __restrict__ mixed_inv, bf16* __restrict__ aa_emb)
{
    int r = blockIdx.x;
    int d = threadIdx.x;
    if (r < B_ * L_) {
        int b = r / L_;
        float v = (float)embh[(long)inv_token[r] * D_ + d] +
                  (float)graph_repr[((long)b * N_ + inv_node[r]) * D_ + d];
        mixed_inv[(long)r * D_ + d] = __float2bfloat16(v);
    } else {
        int r2 = r - B_ * L_;
        int b = r2 / A_;
        float v = (float)embh[(long)aa_token[r2] * D_ + d] +
                  (float)graph_repr[((long)b * N_ + aa_node[r2]) * D_ + d];
        aa_emb[(long)r2 * D_ + d] = __float2bfloat16(v);
    }
}

// ---------------------------------------------------------------------------
// GRU via MFMA, 4 blocks x 4 batches (round-15 version: 16-row hB)
// ---------------------------------------------------------------------------
__global__ __launch_bounds__(1024)
void gru_kernel(const bf16* __restrict__ gxT, const short8* __restrict__ WhhP,
                const float* __restrict__ b_hh, float* __restrict__ inv_out)
{
    __shared__ short hB[2][16 * 264];

    const int tid = threadIdx.x;
    const int lane = tid & 63;
    const int wave = tid >> 6;
    const int quad = lane >> 4, c16 = lane & 15;
    const int n0 = wave * 16 + c16;
    const int bb = blockIdx.x * 4 + quad;

    for (int i = tid; i < 2 * 16 * 264; i += 1024) ((short*)hB)[i] = 0;

    short8 wfr[8], wfz[8], wfn[8];
    #pragma unroll
    for (int tk = 0; tk < 8; ++tk) {
        wfr[tk] = WhhP[((0 * 16 + wave) * 8 + tk) * 64 + lane];
        wfz[tk] = WhhP[((1 * 16 + wave) * 8 + tk) * 64 + lane];
        wfn[tk] = WhhP[((2 * 16 + wave) * 8 + tk) * 64 + lane];
    }
    float bhr = b_hh[0 * 256 + n0];
    float bhz = b_hh[1 * 256 + n0];
    float bhn = b_hh[2 * 256 + n0];

    float myh = 0.f;

    const unsigned short* g_r = (const unsigned short*)gxT +
        ((long)blockIdx.x * 64 * 768 + n0) * 4 + quad;
    const unsigned short* g_z = g_r + 256 * 4;
    const unsigned short* g_n = g_r + 512 * 4;

    unsigned short pr = g_r[0], pz = g_z[0], pn = g_n[0];

    __syncthreads();

    int p = 0;
    for (int t = 0; t < L_; ++t) {
        float xr = __uint_as_float((unsigned)pr << 16);
        float xz = __uint_as_float((unsigned)pz << 16);
        float xn = __uint_as_float((unsigned)pn << 16);
        long noff = (long)((t + 1 < L_) ? t + 1 : t) * 3072;
        pr = g_r[noff]; pz = g_z[noff]; pn = g_n[noff];

        f32x4 ar = (f32x4){bhr, bhr, bhr, bhr};
        f32x4 az = (f32x4){bhz, bhz, bhz, bhz};
        f32x4 an = (f32x4){bhn, bhn, bhn, bhn};
        const short* hp = &hB[p][0];
        #pragma unroll
        for (int tk = 0; tk < 8; ++tk) {
            short8 a = *(const short8*)&hp[c16 * 264 + tk * 32 + quad * 8];
            ar = __builtin_amdgcn_mfma_f32_16x16x32_bf16(a, wfr[tk], ar, 0, 0, 0);
            az = __builtin_amdgcn_mfma_f32_16x16x32_bf16(a, wfz[tk], az, 0, 0, 0);
            an = __builtin_amdgcn_mfma_f32_16x16x32_bf16(a, wfn[tk], an, 0, 0, 0);
        }

        float rr = fsigm(xr + ar[0]);
        float zz = fsigm(xz + az[0]);
        float cc = ftanh(xn + rr * an[0]);
        myh = (1.f - zz) * cc + zz * myh;
        hB[p ^ 1][(quad * 4) * 264 + n0] = (short)rne1(myh);
        p ^= 1;
        __syncthreads();
    }

    inv_out[(long)bb * 256 + n0] = myh;
}

// ---------------------------------------------------------------------------
// uprep: u[b,d] = Wab[d] + Σ_o Wap[d,o]·inv[b,o];  s0[b] = bab + bap·inv[b]
// ---------------------------------------------------------------------------
__global__ void uprep_kernel(const float* __restrict__ Wap, const float* __restrict__ Wab,
                             const float* __restrict__ bap, const float* __restrict__ bab,
                             const float* __restrict__ inv, float* __restrict__ u,
                             float* __restrict__ s0)
{
    int b = blockIdx.x, d = threadIdx.x;
    __shared__ float iv[256];
    iv[d] = inv[(long)b * 256 + d];
    __syncthreads();
    float s = Wab[d];
    const float* wr = Wap + (long)d * 256;
    #pragma unroll 8
    for (int o = 0; o < 256; ++o) s += wr[o] * iv[o];
    u[(long)b * 256 + d] = s;
    if (d == 0) {
        float t = bab[0];
        for (int o = 0; o < 256; ++o) t += bap[o] * iv[o];
        s0[b] = t;
    }
}

// ---------------------------------------------------------------------------
// scores: out[r] = aa_emb[r]·u[b] + s0[b] + log-mask
// ---------------------------------------------------------------------------
__global__ void score_kernel(const bf16* __restrict__ aa_emb, const float* __restrict__ u,
                             const float* __restrict__ s0, const float* __restrict__ mask,
                             float* __restrict__ out)
{
    int r = blockIdx.x * 4 + (threadIdx.x >> 6);
    int l = threadIdx.x & 63;
    int b = r / A_;
    float s = 0.f;
    for (int d = l; d < D_; d += 64)
        s += (float)aa_emb[(long)r * D_ + d] * u[(long)b * D_ + d];
    #pragma unroll
    for (int off = 32; off; off >>= 1) s += __shfl_down(s, off);
    if (l == 0) {
        float lm = logf(mask[r]);
        const float MN = -3.4028234663852886e38f;
        if (!(lm >= MN)) lm = MN;
        out[r] = s + s0[b] + lm;
    }
}

// ---------------------------------------------------------------------------
// host
// ---------------------------------------------------------------------------
static inline size_t align256(size_t x) { return (x + 255) & ~(size_t)255; }

template <typename CT>
static void launch_pgemm(const bf16* A, const int* arows, const unsigned* Bp,
                         const float* bias, CT* C, int M, int K, int Nc, int relu,
                         long astride, int aoff, int colbase, int hslice, int addC,
                         int outT, int ncols, hipStream_t s)
{
    dim3 grid(ncols / TN, (M + TM - 1) / TM);
    pgemm_kernel<CT><<<grid, 256, 0, s>>>(A, arows, Bp, bias, C, M, K, Nc, relu,
                                          astride, aoff, colbase, hslice, addC, outT);
}

extern "C" void kernel_launch(void* const* d_in, const int* in_sizes, int n_in,
                              void* d_out, int out_size, void* d_ws, size_t ws_size,
                              hipStream_t stream)
{
    const int* node_tokens = (const int*)d_in[0];
    const int* edge_tokens = (const int*)d_in[1];
    const int* edge_index  = (const int*)d_in[2];
    const int* inv_token   = (const int*)d_in[3];
    const int* inv_node    = (const int*)d_in[4];
    const int* aa_token    = (const int*)d_in[5];
    const int* aa_node     = (const int*)d_in[6];
    const float* action_mask = (const float*)d_in[7];
    const float* emb   = (const float*)d_in[8];
    const float* Wq    = (const float*)d_in[9];
    const float* bq    = (const float*)d_in[10];
    const float* Wk    = (const float*)d_in[11];
    const float* bk    = (const float*)d_in[12];
    const float* Wv    = (const float*)d_in[13];
    const float* bv    = (const float*)d_in[14];
    const float* We    = (const float*)d_in[15];
    const float* Wskip = (const float*)d_in[16];
    const float* bskip = (const float*)d_in[17];
    const float* W1    = (const float*)d_in[18];
    const float* b1    = (const float*)d_in[19];
    const float* Wp    = (const float*)d_in[20];
    const float* bp    = (const float*)d_in[21];
    const float* W_ih  = (const float*)d_in[22];
    const float* W_hh  = (const float*)d_in[23];
    const float* b_ih  = (const float*)d_in[24];
    const float* b_hh  = (const float*)d_in[25];
    const float* Wab   = (const float*)d_in[26];
    const float* bab   = (const float*)d_in[27];
    const float* Wap   = (const float*)d_in[28];
    const float* bap   = (const float*)d_in[29];
    (void)in_sizes; (void)n_in; (void)out_size;

    char* base = (char*)d_ws;
    size_t off = 0;
    auto alloc = [&](size_t bytes) -> char* {
        char* p = base + off;
        off = align256(off + bytes);
        return p;
    };

    // persistent buffers
    const long VD = 50000L * 256;
    bf16*  embh       = (bf16*)alloc(VD * 2);
    bf16*  graph_repr = (bf16*)alloc((size_t)B_ * N_ * D_ * 2);
    bf16*  mixed_inv  = (bf16*)alloc((size_t)B_ * L_ * D_ * 2);
    bf16*  inv_h      = (bf16*)alloc((size_t)B_ * L_ * D_ * 2);
    bf16*  gxT        = (bf16*)alloc((size_t)B_ * L_ * 768 * 2);
    float* inv_out    = (float*)alloc((size_t)B_ * 256 * 4);
    bf16*  aa_emb     = (bf16*)alloc((size_t)B_ * A_ * D_ * 2);
    float* ubuf       = (float*)alloc((size_t)B_ * 256 * 4);
    float* s0buf      = (float*)alloc((size_t)B_ * 4);
    unsigned* qkvsP   = (unsigned*)alloc((size_t)128 * QS * 4);
    unsigned* WeP     = (unsigned*)alloc((size_t)128 * 1024 * 4);
    unsigned* W1P     = (unsigned*)alloc((size_t)512 * 256 * 4);
    unsigned* WpP     = (unsigned*)alloc((size_t)128 * 256 * 4);
    unsigned* WihP    = (unsigned*)alloc((size_t)128 * 768 * 4);
    short8* WhhP      = (short8*)alloc((size_t)24576 * 16);
    float* bias5120   = (float*)alloc(QS * 4);
    size_t persist = off;

    // batch-chunk size
    int c = 16;
    while (c > 1) {
        size_t cN = (size_t)c * N_, cEs = (size_t)c * E_;
        size_t chunk = align256(cN * QS * 2)
                     + align256(cN * HD_ * 2)
                     + align256(cN * HD_ * 2)
                     + 2 * align256(cN * 4)
                     + align256(cEs * 4);
        if (persist + chunk <= ws_size) break;
        c >>= 1;
    }
    int cN = c * N_, cE = c * E_;

    bf16*  qkvs  = (bf16*)alloc((size_t)cN * QS * 2);
    bf16*  aggb  = (bf16*)alloc((size_t)cN * HD_ * 2);
    bf16*  xsumb = (bf16*)alloc((size_t)cN * HD_ * 2);
    int*   cnt   = (int*)alloc((size_t)cN * 4);
    int*   rstart= (int*)alloc((size_t)cN * 4);
    int*   elist = (int*)alloc((size_t)cE * 4);

    // ---- pre-pass ----
    convemb_kernel<<<(int)((VD / 4 + 255) / 256), 256, 0, stream>>>(emb, embh, VD / 4);
    pack_all_kernel<<<(PACK_ALL_TOT + 255) / 256, 256, 0, stream>>>(
        Wq, Wk, Wv, Wskip, We, W1, Wp, W_ih, W_hh, bq, bk, bv, bskip,
        qkvsP, WeP, W1P, WpP, WihP, WhhP, bias5120);
    wqe_kernel<<<512, 256, 0, stream>>>(Wq, We, bq, qkvsP, bias5120);

    for (int b0 = 0; b0 < B_; b0 += c) {
        csr_kernel<<<c, 1024, 0, stream>>>(edge_index, b0, rstart, cnt, elist);
        launch_pgemm<bf16>(embh, node_tokens + (long)b0 * N_, qkvsP, bias5120, qkvs,
                           cN, D_, QS, 0, 256, 0, 0, 0, 0, 0, QS, stream);
        attn_kernel<<<cN, 256, 0, stream>>>(qkvs, embh, edge_tokens, edge_index,
                                            rstart, cnt, elist, b0, aggb, xsumb);
        launch_pgemm<bf16>(xsumb, nullptr, WeP, nullptr, aggb,
                           cN, 256, 1024, 1, 1024, 0, 0, 1, 1, 0, 1024, stream);
        launch_pgemm<bf16>(aggb, nullptr, W1P, b1,
                           graph_repr + (long)b0 * N_ * D_,
                           cN, HD_, D_, 1, 1024, 0, 0, 0, 0, 0, 256, stream);
    }

    // invariant + action embeds (fused)
    mixed2_kernel<<<B_ * L_ + B_ * A_, 256, 0, stream>>>(embh, inv_token, inv_node,
                                                         aa_token, aa_node, graph_repr,
                                                         mixed_inv, aa_emb);
    launch_pgemm<bf16>(mixed_inv, nullptr, WpP, bp, inv_h,
                       B_ * L_, D_, 256, 1, 256, 0, 0, 0, 0, 0, 256, stream);
    launch_pgemm<bf16>(inv_h, nullptr, WihP, b_ih, gxT,
                       B_ * L_, 256, 768, 0, 256, 0, 0, 0, 0, 1, 768, stream);
    gru_kernel<<<4, 1024, 0, stream>>>(gxT, WhhP, b_hh, inv_out);

    // action path
    uprep_kernel<<<B_, 256, 0, stream>>>(Wap, Wab, bap, bab, inv_out, ubuf, s0buf);
    score_kernel<<<(B_ * A_) / 4, 256, 0, stream>>>(aa_emb, ubuf, s0buf,
                                                    action_mask, (float*)d_out);
}